// Round 2
// baseline (1264.233 us; speedup 1.0000x reference)
//
#include <hip/hip_runtime.h>
#include <hip/hip_bf16.h>

#define NA 100000
#define KN 6
#define NBOND 200000
#define AFEAT 133
#define BFEAT 14
#define HD 256

typedef __attribute__((ext_vector_type(4))) float f32x4;
typedef __attribute__((ext_vector_type(8))) __bf16 bf16x8;
typedef __attribute__((ext_vector_type(4))) __bf16 bf16x4;
typedef __attribute__((ext_vector_type(8))) short s16x8;
typedef __attribute__((ext_vector_type(4))) short s16x4;

__device__ inline unsigned short f2u(float f){
    __hip_bfloat16 h = __float2bfloat16(f);
    return *reinterpret_cast<unsigned short*>(&h);
}

// ---------------------------------------------------------------------------
// Pack all weight matrices [K x 256] (f32) into bf16 MFMA B-fragment order:
// group gid -> (kc,cbg,quad,l16); elem j: k = kc*32+quad*8+j, col = cbg*16+l16
// Zero-pads k >= K. Total groups = 95232 (x8 elems).
// ---------------------------------------------------------------------------
__global__ __launch_bounds__(256) void pack_weights(
    const float* __restrict__ wi, const float* __restrict__ wh0,
    const float* __restrict__ wh1, const float* __restrict__ wah0,
    const float* __restrict__ wah, const float* __restrict__ wo,
    unsigned short* __restrict__ dst)
{
    int gid = blockIdx.x * 256 + threadIdx.x;
    if (gid >= 95232) return;
    const int starts[12] = {0,5120,14336,23552,32768,40960,49152,57344,62464,70656,78848,95232};
    int seg = 0;
    while (gid >= starts[seg+1]) seg++;
    int u = gid - starts[seg];
    const float* src; int K;
    if (seg == 0)      { src = wi;                        K = 133; }
    else if (seg < 4)  { src = wh0 + (seg-1)*69120;       K = 270; }
    else if (seg < 7)  { src = wh1 + (seg-4)*65536;       K = 256; }
    else if (seg == 7) { src = wah0;                      K = 133; }
    else if (seg < 10) { src = wah + (seg-8)*65536;       K = 256; }
    else               { src = wo;                        K = 512; }
    int l16 = u & 15, quad = (u >> 4) & 3, cbg = (u >> 6) & 15, kc = u >> 10;
    int col = cbg * 16 + l16;
    s16x8 v;
    #pragma unroll
    for (int j = 0; j < 8; j++){
        int k = kc * 32 + quad * 8 + j;
        ((unsigned short*)&v)[j] = (k < K) ? f2u(src[(size_t)k * 256 + col]) : (unsigned short)0;
    }
    *(s16x8*)(void*)(dst + (size_t)gid * 8) = v;
}

// ---------------------------------------------------------------------------
// Fused GEMM: C = A[M x K] @ Wpacked + bias, epilogue:
//   MODE 0: LayerNorm(g,bt) + PReLU(alpha) -> out (bf16 if !F32OUT else f32), stride ldo
//   MODE 1: zero row 0 -> f32 msg
//   MODE 2: msg += result, zero row 0 -> f32 msg
// A is bf16 (ABF16, 16B-aligned rows) or f32 (scalar loads, converted).
// Block: 256 threads = 4 waves; tile 64 rows x 256 cols (wave w owns cols [64w,64w+64)).
// ---------------------------------------------------------------------------
template<int MODE, bool ABF16, bool F32OUT>
__global__ __launch_bounds__(256) void gemm_fused(
    const void* __restrict__ Aa_, int lda, int K, int KC,
    const unsigned short* __restrict__ Bp,
    const float* __restrict__ bias,
    const float* __restrict__ gw,
    const float* __restrict__ bw,
    const float* __restrict__ alphaP,
    void* __restrict__ outP, int ldo,
    float* __restrict__ msg)
{
    __shared__ unsigned short As[64 * 40];   // 80B row stride: 2-way bank aliasing only (free)
    __shared__ float red[4][128];
    __shared__ float stats[128];

    const int tid  = threadIdx.x;
    const int w    = tid >> 6;
    const int l    = tid & 63;
    const int quad = l >> 4;
    const int l16  = l & 15;
    const long rowbase = (long)blockIdx.x * 64;

    f32x4 acc[4][4];
    #pragma unroll
    for (int i = 0; i < 4; i++)
        #pragma unroll
        for (int j = 0; j < 4; j++)
            acc[i][j] = (f32x4){0.f, 0.f, 0.f, 0.f};

    const int sr = tid >> 2;          // staging row 0..63
    const int sk = (tid & 3) * 8;     // staging k offset 0/8/16/24
    const long grow_s = rowbase + sr;

    for (int kc = 0; kc < KC; ++kc){
        const int k0 = kc * 32;
        s16x8 v = (s16x8){0,0,0,0,0,0,0,0};
        if (grow_s < NA){
            if (ABF16){
                v = *(const s16x8*)(const void*)((const unsigned short*)Aa_ + grow_s * (size_t)lda + k0 + sk);
            } else {
                const float* Af = (const float*)Aa_;
                #pragma unroll
                for (int j = 0; j < 8; j++){
                    int k = k0 + sk + j;
                    ((unsigned short*)&v)[j] = (k < K) ? f2u(Af[grow_s * (size_t)lda + k]) : (unsigned short)0;
                }
            }
        }
        *(s16x4*)(void*)(As + sr * 40 + sk)     = ((s16x4*)&v)[0];
        *(s16x4*)(void*)(As + sr * 40 + sk + 4) = ((s16x4*)&v)[1];
        __syncthreads();

        bf16x8 afr[4], bfr[4];
        #pragma unroll
        for (int rb = 0; rb < 4; rb++){
            const unsigned short* p = As + (rb * 16 + l16) * 40 + quad * 8;
            ((bf16x4*)&afr[rb])[0] = *(const bf16x4*)(const void*)p;
            ((bf16x4*)&afr[rb])[1] = *(const bf16x4*)(const void*)(p + 4);
        }
        #pragma unroll
        for (int cb = 0; cb < 4; cb++){
            size_t off = ((((size_t)kc * 16 + (w * 4 + cb)) * 4 + quad) * 16 + l16) * 8;
            bfr[cb] = *(const bf16x8*)(const void*)(Bp + off);
        }
        #pragma unroll
        for (int rb = 0; rb < 4; rb++)
            #pragma unroll
            for (int cb = 0; cb < 4; cb++)
                acc[rb][cb] = __builtin_amdgcn_mfma_f32_16x16x32_bf16(afr[rb], bfr[cb], acc[rb][cb], 0, 0, 0);
        __syncthreads();
    }

    // bias add (feeds LN in MODE 0)
    float biasf[4];
    #pragma unroll
    for (int cb = 0; cb < 4; cb++) biasf[cb] = bias[w * 64 + cb * 16 + l16];
    #pragma unroll
    for (int rb = 0; rb < 4; rb++)
        #pragma unroll
        for (int cb = 0; cb < 4; cb++)
            #pragma unroll
            for (int r = 0; r < 4; r++)
                acc[rb][cb][r] += biasf[cb];

    if constexpr (MODE == 0){
        #pragma unroll
        for (int rb = 0; rb < 4; rb++){
            #pragma unroll
            for (int r = 0; r < 4; r++){
                float a0 = acc[rb][0][r], a1 = acc[rb][1][r], a2 = acc[rb][2][r], a3 = acc[rb][3][r];
                float s = a0 + a1 + a2 + a3;
                float q = a0*a0 + a1*a1 + a2*a2 + a3*a3;
                #pragma unroll
                for (int m = 1; m < 16; m <<= 1){
                    s += __shfl_xor(s, m, 64);
                    q += __shfl_xor(q, m, 64);
                }
                if (l16 == 0){
                    int row = rb * 16 + quad * 4 + r;
                    red[w][row * 2]     = s;
                    red[w][row * 2 + 1] = q;
                }
            }
        }
        __syncthreads();
        if (tid < 64){
            float S1 = red[0][tid*2]   + red[1][tid*2]   + red[2][tid*2]   + red[3][tid*2];
            float S2 = red[0][tid*2+1] + red[1][tid*2+1] + red[2][tid*2+1] + red[3][tid*2+1];
            float mu  = S1 * (1.0f / 256.0f);
            float var = S2 * (1.0f / 256.0f) - mu * mu;
            stats[tid*2]     = mu;
            stats[tid*2 + 1] = rsqrtf(var + 1e-5f);
        }
        __syncthreads();
        float al = alphaP[0];
        float gf[4], btf[4];
        #pragma unroll
        for (int cb = 0; cb < 4; cb++){
            int c = w * 64 + cb * 16 + l16;
            gf[cb]  = gw[c];
            btf[cb] = bw[c];
        }
        #pragma unroll
        for (int rb = 0; rb < 4; rb++){
            #pragma unroll
            for (int r = 0; r < 4; r++){
                int row = rb * 16 + quad * 4 + r;
                long grow = rowbase + row;
                if (grow < NA){
                    float mu = stats[row*2], rs = stats[row*2 + 1];
                    #pragma unroll
                    for (int cb = 0; cb < 4; cb++){
                        int c = w * 64 + cb * 16 + l16;
                        float y = (acc[rb][cb][r] - mu) * rs * gf[cb] + btf[cb];
                        y = (y >= 0.f) ? y : al * y;
                        if (F32OUT)
                            ((float*)outP)[(size_t)grow * ldo + c] = y;
                        else
                            ((unsigned short*)outP)[(size_t)grow * ldo + c] = f2u(y);
                    }
                }
            }
        }
    } else {
        #pragma unroll
        for (int rb = 0; rb < 4; rb++){
            #pragma unroll
            for (int r = 0; r < 4; r++){
                int row = rb * 16 + quad * 4 + r;
                long grow = rowbase + row;
                if (grow < NA){
                    #pragma unroll
                    for (int cb = 0; cb < 4; cb++){
                        int c = w * 64 + cb * 16 + l16;
                        float y = acc[rb][cb][r];
                        if constexpr (MODE == 2) y += msg[(size_t)grow * 256 + c];
                        if (grow == 0) y = 0.f;
                        msg[(size_t)grow * 256 + c] = y;
                    }
                }
            }
        }
    }
}

// ---------------------------------------------------------------------------
// Gather-sum: m_in[n] = concat( sum_k msg[a2a[n,k]], sum_k f_bonds[a2b[n,k]], 0-pad to 288 )
// One wave per atom, 4 atoms per block. msg f32, f_bonds f32, output bf16.
// ---------------------------------------------------------------------------
__global__ __launch_bounds__(256) void gather_min(
    const float* __restrict__ msg, const float* __restrict__ f_bonds,
    const int* __restrict__ a2a, const int* __restrict__ a2b,
    unsigned short* __restrict__ m_in)
{
    int w = threadIdx.x >> 6, l = threadIdx.x & 63;
    int n = blockIdx.x * 4 + w;
    if (n >= NA) return;
    const int* ra = a2a + n * KN;
    float s0 = 0.f, s1 = 0.f, s2 = 0.f, s3 = 0.f;
    #pragma unroll
    for (int k = 0; k < KN; k++){
        const float* mr = msg + (size_t)ra[k] * 256;
        s0 += mr[l]; s1 += mr[l + 64]; s2 += mr[l + 128]; s3 += mr[l + 192];
    }
    unsigned short* dst = m_in + (size_t)n * 288;
    dst[l] = f2u(s0); dst[l + 64] = f2u(s1); dst[l + 128] = f2u(s2); dst[l + 192] = f2u(s3);
    if (l < BFEAT){
        const int* rb = a2b + n * KN;
        float sb = 0.f;
        #pragma unroll
        for (int k = 0; k < KN; k++) sb += f_bonds[(size_t)rb[k] * BFEAT + l];
        dst[256 + l] = f2u(sb);
    } else if (l < 32){
        dst[256 + l] = 0;   // zero pad cols 270..287
    }
}

// ---------------------------------------------------------------------------
// a_message = PReLU(LN(sum_k msg[a2a[n,k]], tune_g, tune_b), tune_a) -> a_input[:,256:512] (bf16)
// ---------------------------------------------------------------------------
__global__ __launch_bounds__(256) void gather_amsg(
    const float* __restrict__ msg, const int* __restrict__ a2a,
    const float* __restrict__ g, const float* __restrict__ bt,
    const float* __restrict__ aP, unsigned short* __restrict__ a_inp)
{
    int w = threadIdx.x >> 6, l = threadIdx.x & 63;
    int n = blockIdx.x * 4 + w;
    if (n >= NA) return;
    const int* ra = a2a + n * KN;
    float s[4] = {0.f, 0.f, 0.f, 0.f};
    #pragma unroll
    for (int k = 0; k < KN; k++){
        const float* mr = msg + (size_t)ra[k] * 256;
        s[0] += mr[l]; s[1] += mr[l + 64]; s[2] += mr[l + 128]; s[3] += mr[l + 192];
    }
    float p1 = s[0] + s[1] + s[2] + s[3];
    float p2 = s[0]*s[0] + s[1]*s[1] + s[2]*s[2] + s[3]*s[3];
    #pragma unroll
    for (int m = 1; m < 64; m <<= 1){
        p1 += __shfl_xor(p1, m, 64);
        p2 += __shfl_xor(p2, m, 64);
    }
    float mu  = p1 * (1.0f / 256.0f);
    float var = p2 * (1.0f / 256.0f) - mu * mu;
    float rs  = rsqrtf(var + 1e-5f);
    float al  = aP[0];
    unsigned short* dst = a_inp + (size_t)n * 512 + 256;
    #pragma unroll
    for (int j = 0; j < 4; j++){
        int c = l + j * 64;
        float y = (s[j] - mu) * rs * g[c] + bt[c];
        y = (y >= 0.f) ? y : al * y;
        dst[c] = f2u(y);
    }
}

// ---------------------------------------------------------------------------
extern "C" void kernel_launch(void* const* d_in, const int* in_sizes, int n_in,
                              void* d_out, int out_size, void* d_ws, size_t ws_size,
                              hipStream_t stream)
{
    const float* f_atoms = (const float*)d_in[0];
    const float* f_bonds = (const float*)d_in[1];
    const float* wi_w    = (const float*)d_in[2];
    const float* wi_b    = (const float*)d_in[3];
    const float* wh0_w   = (const float*)d_in[4];
    const float* wh0_b   = (const float*)d_in[5];
    const float* wh_g    = (const float*)d_in[6];
    const float* wh_bt   = (const float*)d_in[7];
    const float* wh_a    = (const float*)d_in[8];
    const float* wh1_w   = (const float*)d_in[9];
    const float* wh1_b   = (const float*)d_in[10];
    const float* tune_g  = (const float*)d_in[11];
    const float* tune_b  = (const float*)d_in[12];
    const float* tune_a  = (const float*)d_in[13];
    const float* wah0_w  = (const float*)d_in[14];
    const float* wah0_b  = (const float*)d_in[15];
    const float* wah0_g  = (const float*)d_in[16];
    const float* wah0_bt = (const float*)d_in[17];
    const float* wah0_a  = (const float*)d_in[18];
    const float* wah_w   = (const float*)d_in[19];
    const float* wah_b   = (const float*)d_in[20];
    const float* wah_g   = (const float*)d_in[21];
    const float* wah_bt  = (const float*)d_in[22];
    const float* wah_a   = (const float*)d_in[23];
    const float* wo_w    = (const float*)d_in[24];
    const float* wo_b    = (const float*)d_in[25];
    const float* wo_g    = (const float*)d_in[26];
    const float* wo_bt   = (const float*)d_in[27];
    const float* wo_a    = (const float*)d_in[28];
    const int* a2a = (const int*)d_in[29];
    const int* a2b = (const int*)d_in[30];

    char* ws = (char*)d_ws;
    float*          msg   = (float*)ws;                              // 102,400,000 B
    unsigned short* m_in  = (unsigned short*)(ws + 102400000LL);     //  57,600,000 B
    unsigned short* tmp   = (unsigned short*)(ws + 160000000LL);     //  51,200,000 B
    unsigned short* cc1   = m_in;                                    // alias (m_in dead by then)
    unsigned short* a_inp = (unsigned short*)(ws + 211200000LL);     // 102,400,000 B
    unsigned short* Wp    = (unsigned short*)(ws + 313600000LL);     //   1,523,712 B

    const int GB = (NA + 63) / 64;   // 1563
    dim3 b256(256);

    pack_weights<<<372, b256, 0, stream>>>(wi_w, wh0_w, wh1_w, wah0_w, wah_w, wo_w, Wp);

    // h = f_atoms @ wi_w + wi_b ; row 0 <- 0 ; msg (f32)
    gemm_fused<1, false, false><<<GB, b256, 0, stream>>>(f_atoms, 133, 133, 5, Wp + 0,
        wi_b, nullptr, nullptr, nullptr, nullptr, 0, msg);

    for (int d = 0; d < 3; ++d){
        gather_min<<<NA/4, b256, 0, stream>>>(msg, f_bonds, a2a, a2b, m_in);
        // m1 = PReLU(LN(m_in @ wh_l0_w[d] + b)) -> tmp (bf16)
        gemm_fused<0, true, false><<<GB, b256, 0, stream>>>(m_in, 288, 288, 9, Wp + 40960 + d*73728,
            wh0_b + d*256, wh_g + d*256, wh_bt + d*256, wh_a + d, tmp, 256, nullptr);
        // msg += tmp @ wh_l1_w[d] + b ; row 0 <- 0
        gemm_fused<2, true, false><<<GB, b256, 0, stream>>>(tmp, 256, 256, 8, Wp + 262144 + d*65536,
            wh1_b + d*256, nullptr, nullptr, nullptr, nullptr, 0, msg);
    }

    // a_message -> a_input[:,256:512]
    gather_amsg<<<NA/4, b256, 0, stream>>>(msg, a2a, tune_g, tune_b, tune_a, a_inp);
    // cc chain
    gemm_fused<0, false, false><<<GB, b256, 0, stream>>>(f_atoms, 133, 133, 5, Wp + 458752,
        wah0_b, wah0_g, wah0_bt, wah0_a, tmp, 256, nullptr);
    gemm_fused<0, true, false><<<GB, b256, 0, stream>>>(tmp, 256, 256, 8, Wp + 499712,
        wah_b, wah_g, wah_bt, wah_a, cc1, 256, nullptr);
    gemm_fused<0, true, false><<<GB, b256, 0, stream>>>(cc1, 256, 256, 8, Wp + 565248,
        wah_b + 256, wah_g + 256, wah_bt + 256, wah_a + 1, a_inp, 512, nullptr);
    // out = PReLU(LN(a_input @ wo_w + b)) -> d_out (f32)
    gemm_fused<0, true, true><<<GB, b256, 0, stream>>>(a_inp, 512, 512, 16, Wp + 630784,
        wo_b, wo_g, wo_bt, wo_a, d_out, 256, nullptr);
}

// Round 3
// 1144.227 us; speedup vs baseline: 1.1049x; 1.1049x over previous
//
#include <hip/hip_runtime.h>
#include <hip/hip_bf16.h>

#define NA 100000
#define KN 6

typedef __attribute__((ext_vector_type(4))) float f32x4;
typedef __attribute__((ext_vector_type(8))) __bf16 bf16x8;
typedef __attribute__((ext_vector_type(8))) short s16x8;

__device__ inline unsigned short f2u(float f){
    __hip_bfloat16 h = __float2bfloat16(f);
    return *reinterpret_cast<unsigned short*>(&h);
}

// ---------------------------------------------------------------------------
// Pack all weight matrices [K x 256] (f32) into bf16 MFMA B-fragment order.
// ---------------------------------------------------------------------------
__global__ __launch_bounds__(256) void pack_weights(
    const float* __restrict__ wi, const float* __restrict__ wh0,
    const float* __restrict__ wh1, const float* __restrict__ wah0,
    const float* __restrict__ wah, const float* __restrict__ wo,
    unsigned short* __restrict__ dst)
{
    int gid = blockIdx.x * 256 + threadIdx.x;
    if (gid >= 95232) return;
    const int starts[12] = {0,5120,14336,23552,32768,40960,49152,57344,62464,70656,78848,95232};
    int seg = 0;
    while (gid >= starts[seg+1]) seg++;
    int u = gid - starts[seg];
    const float* src; int K;
    if (seg == 0)      { src = wi;                        K = 133; }
    else if (seg < 4)  { src = wh0 + (seg-1)*69120;       K = 270; }
    else if (seg < 7)  { src = wh1 + (seg-4)*65536;       K = 256; }
    else if (seg == 7) { src = wah0;                      K = 133; }
    else if (seg < 10) { src = wah + (seg-8)*65536;       K = 256; }
    else               { src = wo;                        K = 512; }
    int l16 = u & 15, quad = (u >> 4) & 3, cbg = (u >> 6) & 15, kc = u >> 10;
    int col = cbg * 16 + l16;
    s16x8 v;
    #pragma unroll
    for (int j = 0; j < 8; j++){
        int k = kc * 32 + quad * 8 + j;
        ((unsigned short*)&v)[j] = (k < K) ? f2u(src[(size_t)k * 256 + col]) : (unsigned short)0;
    }
    *(s16x8*)(void*)(dst + (size_t)gid * 8) = v;
}

// ---------------------------------------------------------------------------
// bond_sum[n][0..31] = concat( sum_k f_bonds[a2b[n,k]][0..13], zeros ) as bf16.
// Depth-invariant — computed once.
// ---------------------------------------------------------------------------
__global__ __launch_bounds__(256) void bond_gather(
    const float* __restrict__ f_bonds, const int* __restrict__ a2b,
    unsigned short* __restrict__ bsum)
{
    int t = blockIdx.x * 256 + threadIdx.x;
    int n = t >> 4, c = t & 15;
    if (n >= NA) return;
    float s = 0.f;
    if (c < 14){
        const int* rb = a2b + n * KN;
        #pragma unroll
        for (int k = 0; k < KN; k++) s += f_bonds[(size_t)rb[k] * 14 + c];
    }
    bsum[(size_t)n * 32 + c]      = (c < 14) ? f2u(s) : (unsigned short)0;
    bsum[(size_t)n * 32 + 16 + c] = 0;
}

// ---------------------------------------------------------------------------
// Barrier-free MFMA K-loop from an LDS-resident A tile (64 x >=KC*32, bf16,
// 16B-aligned rows of STRIDE shorts) and L2-resident packed B.
// ---------------------------------------------------------------------------
template<int KC, int STRIDE>
__device__ inline void gemm_lds(const unsigned short* As, const unsigned short* __restrict__ Bp,
                                f32x4 (&acc)[4][4], int w, int quad, int l16)
{
    #pragma unroll
    for (int rb = 0; rb < 4; rb++)
        #pragma unroll
        for (int cb = 0; cb < 4; cb++)
            acc[rb][cb] = (f32x4){0.f, 0.f, 0.f, 0.f};
    #pragma unroll
    for (int kc = 0; kc < KC; kc++){
        bf16x8 afr[4], bfr[4];
        #pragma unroll
        for (int rb = 0; rb < 4; rb++)
            afr[rb] = *(const bf16x8*)(const void*)(As + (rb*16 + l16)*STRIDE + kc*32 + quad*8);
        #pragma unroll
        for (int cb = 0; cb < 4; cb++)
            bfr[cb] = *(const bf16x8*)(const void*)(Bp + ((((size_t)kc*16 + (w*4+cb))*4 + quad)*16 + l16)*8);
        #pragma unroll
        for (int rb = 0; rb < 4; rb++)
            #pragma unroll
            for (int cb = 0; cb < 4; cb++)
                acc[rb][cb] = __builtin_amdgcn_mfma_f32_16x16x32_bf16(afr[rb], bfr[cb], acc[rb][cb], 0, 0, 0);
    }
}

__device__ inline void add_bias(f32x4 (&acc)[4][4], const float* __restrict__ bias, int w, int l16)
{
    #pragma unroll
    for (int cb = 0; cb < 4; cb++){
        float b = bias[w*64 + cb*16 + l16];
        #pragma unroll
        for (int rb = 0; rb < 4; rb++)
            #pragma unroll
            for (int r = 0; r < 4; r++)
                acc[rb][cb][r] += b;
    }
}

// Per-row mean/rstd of the 256-col tile into stats[row*2(+1)]. Two barriers.
__device__ inline void row_stats(f32x4 (&acc)[4][4], float (*red)[128], float* stats,
                                 int tid, int w, int quad, int l16)
{
    #pragma unroll
    for (int rb = 0; rb < 4; rb++){
        #pragma unroll
        for (int r = 0; r < 4; r++){
            float a0 = acc[rb][0][r], a1 = acc[rb][1][r], a2 = acc[rb][2][r], a3 = acc[rb][3][r];
            float s = a0 + a1 + a2 + a3;
            float q = a0*a0 + a1*a1 + a2*a2 + a3*a3;
            #pragma unroll
            for (int m = 1; m < 16; m <<= 1){
                s += __shfl_xor(s, m, 64);
                q += __shfl_xor(q, m, 64);
            }
            if (l16 == 0){
                int row = rb*16 + quad*4 + r;
                red[w][row*2]   = s;
                red[w][row*2+1] = q;
            }
        }
    }
    __syncthreads();
    if (tid < 64){
        float S1 = red[0][tid*2]   + red[1][tid*2]   + red[2][tid*2]   + red[3][tid*2];
        float S2 = red[0][tid*2+1] + red[1][tid*2+1] + red[2][tid*2+1] + red[3][tid*2+1];
        float mu  = S1 * (1.0f/256.0f);
        float var = S2 * (1.0f/256.0f) - mu*mu;
        stats[tid*2]   = mu;
        stats[tid*2+1] = rsqrtf(var + 1e-5f);
    }
    __syncthreads();
}

// LN+PReLU applied to acc, result written as bf16 into LDS tile cols 0..255.
template<int STRIDE>
__device__ inline void ln_apply_lds(const f32x4 (&acc)[4][4], const float* stats,
    const float* __restrict__ g, const float* __restrict__ bt, float al,
    unsigned short* As, int w, int quad, int l16)
{
    #pragma unroll
    for (int cb = 0; cb < 4; cb++){
        int c = w*64 + cb*16 + l16;
        float gf = g[c], btf = bt[c];
        #pragma unroll
        for (int rb = 0; rb < 4; rb++)
            #pragma unroll
            for (int r = 0; r < 4; r++){
                int row = rb*16 + quad*4 + r;
                float y = (acc[rb][cb][r] - stats[row*2]) * stats[row*2+1] * gf + btf;
                y = (y >= 0.f) ? y : al * y;
                As[row*STRIDE + c] = f2u(y);
            }
    }
}

// ---------------------------------------------------------------------------
// init: msg = (f_atoms @ wi + b), row0 = 0 -> msg_f32 + msg_bf shadow
// ---------------------------------------------------------------------------
__global__ __launch_bounds__(256) void init_gemm(
    const float* __restrict__ fa, const unsigned short* __restrict__ Bp,
    const float* __restrict__ bias, float* __restrict__ msgf,
    unsigned short* __restrict__ msgb)
{
    __shared__ __align__(16) unsigned short As[64 * 168];
    const int tid = threadIdx.x, w = tid>>6, l = tid&63, quad = l>>4, l16 = l&15;
    const long rowbase = (long)blockIdx.x * 64;
    const int sr = tid >> 2, sk = (tid & 3) * 8;
    const long ns = rowbase + sr;
    #pragma unroll
    for (int kc = 0; kc < 5; kc++){
        bf16x8 v;
        #pragma unroll
        for (int j = 0; j < 8; j++){
            int k = kc*32 + sk + j;
            float x = (ns < NA && k < 133) ? fa[ns*133 + k] : 0.f;
            v[j] = (__bf16)x;
        }
        *(bf16x8*)(void*)(As + sr*168 + kc*32 + sk) = v;
    }
    __syncthreads();
    f32x4 acc[4][4];
    gemm_lds<5,168>(As, Bp, acc, w, quad, l16);
    float bb[4];
    #pragma unroll
    for (int cb = 0; cb < 4; cb++) bb[cb] = bias[w*64 + cb*16 + l16];
    #pragma unroll
    for (int rb = 0; rb < 4; rb++)
        #pragma unroll
        for (int r = 0; r < 4; r++){
            int row = rb*16 + quad*4 + r;
            long grow = rowbase + row;
            if (grow < NA){
                #pragma unroll
                for (int cb = 0; cb < 4; cb++){
                    int c = w*64 + cb*16 + l16;
                    float y = acc[rb][cb][r] + bb[cb];
                    if (grow == 0) y = 0.f;
                    msgf[grow*256 + c] = y;
                    msgb[grow*256 + c] = f2u(y);
                }
            }
        }
}

// ---------------------------------------------------------------------------
// One fused depth iteration:
//   gather(msg_bf_in, bond_sum) -> LDS A[64x288]
//   GEMM1(K=288) + LN + PReLU -> LDS m1[64x256]
//   GEMM2(K=256) + bias + residual(msg_f32) , row0=0 -> msg_f32, msg_bf_out
// msg_f32 rows are RMW'd only by the owning block; cross-block reads go
// through the bf16 ping-pong shadow -> no race.
// ---------------------------------------------------------------------------
__global__ __launch_bounds__(256) void depth_step(
    const unsigned short* __restrict__ msgb_in, const unsigned short* __restrict__ bsum,
    const int* __restrict__ a2a,
    const unsigned short* __restrict__ Bp1, const float* __restrict__ b1,
    const float* __restrict__ g1, const float* __restrict__ bt1, const float* __restrict__ a1,
    const unsigned short* __restrict__ Bp2, const float* __restrict__ b2,
    float* __restrict__ msgf, unsigned short* __restrict__ msgb_out)
{
    __shared__ __align__(16) unsigned short As[64 * 296];
    __shared__ float red[4][128];
    __shared__ float stats[128];
    const int tid = threadIdx.x, w = tid>>6, l = tid&63, quad = l>>4, l16 = l&15;
    const int h = tid >> 5, lane32 = tid & 31;
    const long rowbase = (long)blockIdx.x * 64;

    // ---- gather phase: half-wave per row, 8 rows each ----
    #pragma unroll
    for (int i = 0; i < 8; i++){
        int r = i*8 + h;
        long n = rowbase + r;
        float s[8] = {0.f,0.f,0.f,0.f,0.f,0.f,0.f,0.f};
        if (n < NA){
            const int* ra = a2a + n*KN;
            int idx[KN];
            #pragma unroll
            for (int k = 0; k < KN; k++) idx[k] = ra[k];
            #pragma unroll
            for (int k = 0; k < KN; k++){
                bf16x8 v = *(const bf16x8*)(const void*)(msgb_in + (size_t)idx[k]*256 + lane32*8);
                #pragma unroll
                for (int j = 0; j < 8; j++) s[j] += (float)v[j];
            }
        }
        bf16x8 o;
        #pragma unroll
        for (int j = 0; j < 8; j++) o[j] = (__bf16)s[j];
        *(bf16x8*)(void*)(As + r*296 + lane32*8) = o;
        if (lane32 < 4){
            bf16x8 bv;
            if (n < NA) bv = *(const bf16x8*)(const void*)(bsum + (size_t)n*32 + lane32*8);
            else {
                #pragma unroll
                for (int j = 0; j < 8; j++) bv[j] = (__bf16)0.f;
            }
            *(bf16x8*)(void*)(As + r*296 + 256 + lane32*8) = bv;
        }
    }
    __syncthreads();

    f32x4 acc[4][4];
    gemm_lds<9,296>(As, Bp1, acc, w, quad, l16);
    add_bias(acc, b1, w, l16);
    row_stats(acc, red, stats, tid, w, quad, l16);
    ln_apply_lds<296>(acc, stats, g1, bt1, a1[0], As, w, quad, l16);
    __syncthreads();

    gemm_lds<8,296>(As, Bp2, acc, w, quad, l16);
    float bb[4];
    #pragma unroll
    for (int cb = 0; cb < 4; cb++) bb[cb] = b2[w*64 + cb*16 + l16];
    #pragma unroll
    for (int rb = 0; rb < 4; rb++)
        #pragma unroll
        for (int r = 0; r < 4; r++){
            int row = rb*16 + quad*4 + r;
            long grow = rowbase + row;
            if (grow < NA){
                #pragma unroll
                for (int cb = 0; cb < 4; cb++){
                    int c = w*64 + cb*16 + l16;
                    float y = acc[rb][cb][r] + bb[cb] + msgf[grow*256 + c];
                    if (grow == 0) y = 0.f;
                    msgf[grow*256 + c] = y;
                    msgb_out[grow*256 + c] = f2u(y);
                }
            }
        }
}

// ---------------------------------------------------------------------------
// Fused tail: cc chain (3 GEMMs) + a_message gather/LN + wo GEMM(K=512) + LN.
// ---------------------------------------------------------------------------
__global__ __launch_bounds__(256) void tail_kernel(
    const float* __restrict__ fa,
    const unsigned short* __restrict__ msgb, const int* __restrict__ a2a,
    const unsigned short* __restrict__ Wp,
    const float* __restrict__ wah0_b, const float* __restrict__ wah0_g,
    const float* __restrict__ wah0_bt, const float* __restrict__ wah0_a,
    const float* __restrict__ wah_b, const float* __restrict__ wah_g,
    const float* __restrict__ wah_bt, const float* __restrict__ wah_a,
    const float* __restrict__ tg, const float* __restrict__ tb, const float* __restrict__ ta,
    const float* __restrict__ wo_b, const float* __restrict__ wo_g,
    const float* __restrict__ wo_bt, const float* __restrict__ wo_a,
    float* __restrict__ out)
{
    __shared__ __align__(16) unsigned short As[64 * 520];
    __shared__ float red[4][128];
    __shared__ float stats[128];
    const int tid = threadIdx.x, w = tid>>6, l = tid&63, quad = l>>4, l16 = l&15;
    const long rowbase = (long)blockIdx.x * 64;

    // stage f_atoms (K=133 -> 160, bf16) into cols 0..159
    {
        const int sr = tid >> 2, sk = (tid & 3) * 8;
        const long ns = rowbase + sr;
        #pragma unroll
        for (int kc = 0; kc < 5; kc++){
            bf16x8 v;
            #pragma unroll
            for (int j = 0; j < 8; j++){
                int k = kc*32 + sk + j;
                float x = (ns < NA && k < 133) ? fa[ns*133 + k] : 0.f;
                v[j] = (__bf16)x;
            }
            *(bf16x8*)(void*)(As + sr*520 + kc*32 + sk) = v;
        }
    }
    __syncthreads();

    f32x4 acc[4][4];
    // cc0 = PReLU(LN(f_atoms @ wah0 + b))
    gemm_lds<5,520>(As, Wp + 458752, acc, w, quad, l16);
    add_bias(acc, wah0_b, w, l16);
    row_stats(acc, red, stats, tid, w, quad, l16);
    ln_apply_lds<520>(acc, stats, wah0_g, wah0_bt, wah0_a[0], As, w, quad, l16);
    __syncthreads();
    // cc1
    gemm_lds<8,520>(As, Wp + 499712, acc, w, quad, l16);
    add_bias(acc, wah_b, w, l16);
    row_stats(acc, red, stats, tid, w, quad, l16);
    ln_apply_lds<520>(acc, stats, wah_g, wah_bt, wah_a[0], As, w, quad, l16);
    __syncthreads();
    // cc2 -> cols 0..255
    gemm_lds<8,520>(As, Wp + 565248, acc, w, quad, l16);
    add_bias(acc, wah_b + 256, w, l16);
    row_stats(acc, red, stats, tid, w, quad, l16);
    ln_apply_lds<520>(acc, stats, wah_g + 256, wah_bt + 256, wah_a[1], As, w, quad, l16);

    // a_message gather + LN + PReLU -> cols 256..511 (disjoint from cc2 writes)
    {
        const int h = tid >> 5, lane32 = tid & 31;
        const float talpha = ta[0];
        #pragma unroll
        for (int i = 0; i < 8; i++){
            int r = i*8 + h;
            long n = rowbase + r;
            float s[8] = {0.f,0.f,0.f,0.f,0.f,0.f,0.f,0.f};
            if (n < NA){
                const int* ra = a2a + n*KN;
                int idx[KN];
                #pragma unroll
                for (int k = 0; k < KN; k++) idx[k] = ra[k];
                #pragma unroll
                for (int k = 0; k < KN; k++){
                    bf16x8 v = *(const bf16x8*)(const void*)(msgb + (size_t)idx[k]*256 + lane32*8);
                    #pragma unroll
                    for (int j = 0; j < 8; j++) s[j] += (float)v[j];
                }
            }
            float p1 = 0.f, p2 = 0.f;
            #pragma unroll
            for (int j = 0; j < 8; j++){ p1 += s[j]; p2 += s[j]*s[j]; }
            #pragma unroll
            for (int m = 1; m < 32; m <<= 1){
                p1 += __shfl_xor(p1, m, 64);
                p2 += __shfl_xor(p2, m, 64);
            }
            float mu  = p1 * (1.0f/256.0f);
            float var = p2 * (1.0f/256.0f) - mu*mu;
            float rs  = rsqrtf(var + 1e-5f);
            bf16x8 o;
            #pragma unroll
            for (int j = 0; j < 8; j++){
                int c = lane32*8 + j;
                float y = (s[j] - mu) * rs * tg[c] + tb[c];
                y = (y >= 0.f) ? y : talpha * y;
                o[j] = (__bf16)y;
            }
            *(bf16x8*)(void*)(As + r*520 + 256 + lane32*8) = o;
        }
    }
    __syncthreads();

    // out = PReLU(LN(a_input @ wo + b))
    gemm_lds<16,520>(As, Wp + 630784, acc, w, quad, l16);
    add_bias(acc, wo_b, w, l16);
    row_stats(acc, red, stats, tid, w, quad, l16);
    {
        const float al = wo_a[0];
        #pragma unroll
        for (int cb = 0; cb < 4; cb++){
            int c = w*64 + cb*16 + l16;
            float gf = wo_g[c], btf = wo_bt[c];
            #pragma unroll
            for (int rb = 0; rb < 4; rb++)
                #pragma unroll
                for (int r = 0; r < 4; r++){
                    int row = rb*16 + quad*4 + r;
                    long grow = rowbase + row;
                    if (grow < NA){
                        float y = (acc[rb][cb][r] - stats[row*2]) * stats[row*2+1] * gf + btf;
                        y = (y >= 0.f) ? y : al * y;
                        out[grow*256 + c] = y;
                    }
                }
        }
    }
}

// ---------------------------------------------------------------------------
extern "C" void kernel_launch(void* const* d_in, const int* in_sizes, int n_in,
                              void* d_out, int out_size, void* d_ws, size_t ws_size,
                              hipStream_t stream)
{
    const float* f_atoms = (const float*)d_in[0];
    const float* f_bonds = (const float*)d_in[1];
    const float* wi_w    = (const float*)d_in[2];
    const float* wi_b    = (const float*)d_in[3];
    const float* wh0_w   = (const float*)d_in[4];
    const float* wh0_b   = (const float*)d_in[5];
    const float* wh_g    = (const float*)d_in[6];
    const float* wh_bt   = (const float*)d_in[7];
    const float* wh_a    = (const float*)d_in[8];
    const float* wh1_w   = (const float*)d_in[9];
    const float* wh1_b   = (const float*)d_in[10];
    const float* tune_g  = (const float*)d_in[11];
    const float* tune_b  = (const float*)d_in[12];
    const float* tune_a  = (const float*)d_in[13];
    const float* wah0_w  = (const float*)d_in[14];
    const float* wah0_b  = (const float*)d_in[15];
    const float* wah0_g  = (const float*)d_in[16];
    const float* wah0_bt = (const float*)d_in[17];
    const float* wah0_a  = (const float*)d_in[18];
    const float* wah_w   = (const float*)d_in[19];
    const float* wah_b   = (const float*)d_in[20];
    const float* wah_g   = (const float*)d_in[21];
    const float* wah_bt  = (const float*)d_in[22];
    const float* wah_a   = (const float*)d_in[23];
    const float* wo_w    = (const float*)d_in[24];
    const float* wo_b    = (const float*)d_in[25];
    const float* wo_g    = (const float*)d_in[26];
    const float* wo_bt   = (const float*)d_in[27];
    const float* wo_a    = (const float*)d_in[28];
    const int* a2a = (const int*)d_in[29];
    const int* a2b = (const int*)d_in[30];

    char* ws = (char*)d_ws;
    float*          msgf  = (float*)ws;                              // 102,400,000 B
    unsigned short* msgb0 = (unsigned short*)(ws + 102400000LL);     //  51,200,000 B
    unsigned short* msgb1 = (unsigned short*)(ws + 153600000LL);     //  51,200,000 B
    unsigned short* bsum  = (unsigned short*)(ws + 204800000LL);     //   6,400,000 B
    unsigned short* Wp    = (unsigned short*)(ws + 211200000LL);     //   1,523,712 B

    const int GB = (NA + 63) / 64;   // 1563
    dim3 b256(256);

    pack_weights<<<372, b256, 0, stream>>>(wi_w, wh0_w, wh1_w, wah0_w, wah_w, wo_w, Wp);
    bond_gather<<<(NA*16 + 255)/256, b256, 0, stream>>>(f_bonds, a2b, bsum);
    init_gemm<<<GB, b256, 0, stream>>>(f_atoms, Wp + 0, wi_b, msgf, msgb0);

    // depth loop: bf16 shadow ping-pongs
    depth_step<<<GB, b256, 0, stream>>>(msgb0, bsum, a2a,
        Wp + 40960,            wh0_b,       wh_g,       wh_bt,       wh_a,
        Wp + 262144,           wh1_b,       msgf, msgb1);
    depth_step<<<GB, b256, 0, stream>>>(msgb1, bsum, a2a,
        Wp + 40960 + 73728,    wh0_b + 256, wh_g + 256, wh_bt + 256, wh_a + 1,
        Wp + 262144 + 65536,   wh1_b + 256, msgf, msgb0);
    depth_step<<<GB, b256, 0, stream>>>(msgb0, bsum, a2a,
        Wp + 40960 + 147456,   wh0_b + 512, wh_g + 512, wh_bt + 512, wh_a + 2,
        Wp + 262144 + 131072,  wh1_b + 512, msgf, msgb1);

    tail_kernel<<<GB, b256, 0, stream>>>(f_atoms, msgb1, a2a, Wp,
        wah0_b, wah0_g, wah0_bt, wah0_a,
        wah_b, wah_g, wah_bt, wah_a,
        tune_g, tune_b, tune_a,
        wo_b, wo_g, wo_bt, wo_a,
        (float*)d_out);
}